// Round 13
// baseline (378.208 us; speedup 1.0000x reference)
//
#include <hip/hip_runtime.h>

#define T_STEPS 512
#define HID 64

typedef _Float16 f16x8 __attribute__((ext_vector_type(8)));
typedef float f32x4 __attribute__((ext_vector_type(4)));

__device__ __forceinline__ float sigm(float x) {
  return __builtin_amdgcn_rcpf(1.f + __expf(-x));
}
__device__ __forceinline__ float tanh_fast(float x) {
  return 1.f - 2.f * __builtin_amdgcn_rcpf(__expf(2.f * x) + 1.f);
}

// split fp32 -> fp16 hi (round-nearest) + fp16 lo (residual). hi+lo ~ v to 2^-22.
__device__ __forceinline__ void split1(float v, short* hi, short* lo) {
  _Float16 h = (_Float16)v;
  float r = v - (float)h;            // exact in fp32 (h within half-ulp of v)
  _Float16 l = (_Float16)r;
  union { _Float16 f; short s; } uh, ul;
  uh.f = h; ul.f = l;
  *hi = uh.s; *lo = ul.s;
}

__device__ __forceinline__ void cvt8(const float* __restrict__ p, f16x8& w) {
  float v[8];
  *(float4*)&v[0] = *(const float4*)p;
  *(float4*)&v[4] = *(const float4*)(p + 4);
  #pragma unroll
  for (int i = 0; i < 8; ++i) w[i] = (_Float16)v[i];
}

#define MM(acc, A, B)  acc = __builtin_amdgcn_mfma_f32_16x16x32_f16((A), (B), (acc), 0, 0, 0)
#define MMC(A, B, C)   __builtin_amdgcn_mfma_f32_16x16x32_f16((A), (B), (C), 0, 0, 0)

#define WFRAG(NM, Wp, goff) \
  f16x8 NM##c0, NM##c1; \
  cvt8((Wp) + (goff) * (64 * HID) + wrowoff, NM##c0); \
  cvt8((Wp) + (goff) * (64 * HID) + wrowoff + 32, NM##c1)

// In-loop barrier: lgkm-only drain (LDS producer->consumer correctness) + raw
// s_barrier (m201 pattern). No vmcnt drain: the global x prefetch is
// wave-private and floats across barriers.
#define BARRIER() do { \
    asm volatile("s_waitcnt lgkmcnt(0)" ::: "memory"); \
    __builtin_amdgcn_s_barrier(); \
    asm volatile("" ::: "memory"); \
  } while (0)

// fp16 scheme (R12, verified): weights single fp16; values hi/lo in M-rows
// 4b / 4b+1 -> acc[0]+acc[1] = (vh+vl)·W16 exactly. 12 MFMA/wave is the
// structural minimum (6 gate-sides x K64/32 chunks).
// LDS A-matrices: logical [m(16)][k(64)] fp16, XOR-swizzled in 16B units:
// element idx = m*64 + (((k>>3) ^ (m&7))<<3) + (k&7). Conflict-free b128.
//
// Structure: wave specialization by layer (waves 0-3 = L0, 4-7 = L1;
// 2 waves/SIMD), single lgkm-barrier/step, 2x unrolled ping-pong, symmetric
// setprio, x prefetch + early xs write.
// R16: (a) REVERT R13 merge -> split R/Z accumulators: 6 independent 2-deep
// MFMA chains (rr critical path shortens by 2 dependent MFMA completions);
// (b) ALL 12 MFMAs issue before any gate math -- waves issue in-order, so
// sigmoids placed mid-cluster blocked the N-side MFMA issue while waiting
// on the sR chain. Biases ride in the H-side chain heads' C operand.
__global__ __launch_bounds__(512, 2) void gru_mfma(
    const float* __restrict__ x,
    const float* __restrict__ Wih0, const float* __restrict__ Whh0,
    const float* __restrict__ bih0, const float* __restrict__ bhh0,
    const float* __restrict__ Wih1, const float* __restrict__ Whh1,
    const float* __restrict__ bih1, const float* __restrict__ bhh1,
    const float* __restrict__ W1, const float* __restrict__ b1,
    const float* __restrict__ W2, const float* __restrict__ b2,
    float* __restrict__ out)
{
  const int tid   = threadIdx.x;
  const int lane  = tid & 63;
  const int wv    = tid >> 6;      // 0..7
  const int wq    = wv & 3;        // j-chunk
  const int layer = wv >> 2;       // 0: GRU layer 0, 1: GRU layer 1
  const int nloc  = lane & 15;
  const int quad  = lane >> 4;
  const int b0    = blockIdx.x << 2;

  __shared__ __align__(16) short xs[2][1024];
  __shared__ __align__(16) short hA[2][1024];
  __shared__ __align__(16) short hB[2][1024];
  __shared__ float hfin[256];
  __shared__ float msf[128];

  // ---- per-layer weight/bias selection (wave-uniform) ----
  const float* Wih  = layer ? Wih1 : Wih0;
  const float* Whh  = layer ? Whh1 : Whh0;
  const float* bihp = layer ? bih1 : bih0;
  const float* bhhp = layer ? bhh1 : bhh0;

  const int wrowoff = (16 * wq + nloc) * HID + 8 * quad;
  WFRAG(ir, Wih, 0); WFRAG(iz, Wih, 1); WFRAG(in, Wih, 2);
  WFRAG(hr, Whh, 0); WFRAG(hz, Whh, 1); WFRAG(hn, Whh, 2);

  const int jg = 16 * wq + nloc;
  // bias tuples: C operand of each H-side chain head (hoisted, loop-invariant)
  const f32x4 bR4 = {bihp[jg]       + bhhp[jg],       0.f, 0.f, 0.f};
  const f32x4 bZ4 = {bihp[jg + 64]  + bhhp[jg + 64],  0.f, 0.f, 0.f};
  const f32x4 bH4 = {bhhp[jg + 128], 0.f, 0.f, 0.f};
  const f32x4 bI4 = {bihp[jg + 128], 0.f, 0.f, 0.f};
  const f32x4 z4  = {0.f, 0.f, 0.f, 0.f};

  // loop-invariant LDS indices (shorts)
  const int ra0 = nloc * 64 + (((quad    ) ^ (nloc & 7)) << 3);
  const int ra1 = nloc * 64 + (((quad + 4) ^ (nloc & 7)) << 3);
  const int hwrH = quad * 256 +      (((jg >> 3) ^ ( (quad & 1) << 2)     ) << 3) + (jg & 7);
  const int hwrL = quad * 256 + 64 + (((jg >> 3) ^ (((quad & 1) << 2) | 1)) << 3) + (jg & 7);
  const int xwrH = wq * 256 +      (((lane >> 3) ^ ( (wq & 1) << 2)     ) << 3) + (lane & 7);
  const int xwrL = wq * 256 + 64 + (((lane >> 3) ^ (((wq & 1) << 2) | 1)) << 3) + (lane & 7);

  // own-h array (written by this wave's role) and input array (read-only here):
  // L0: own = hA, in = xs;   L1: own = hB, in = hA.
  short* Hown = layer ? &hB[0][0] : &hA[0][0];
  short* Vin  = layer ? &hA[0][0] : &xs[0][0];

  const float* xptr = x + ((size_t)(b0 + wq) * HID + lane) * T_STEPS;

  for (int i = tid; i < 2048; i += 512) {
    ((short*)xs)[i] = 0; ((short*)hA)[i] = 0; ((short*)hB)[i] = 0;
  }
  __syncthreads();
  // iter 0 reads buffer 1: L0 seeds x(0) there (hA, hB stay zero = h(-1))
  if (!layer) { short h, l; split1(xptr[0], &h, &l); xs[1][xwrH] = h; xs[1][xwrL] = l; }
  __syncthreads();

  float hp = 0.f;       // L0: hA[quad][jg]; L1: hB[quad][jg], lagging one step
  float xn_reg = 0.f;   // L0: x(t+1), prefetched one iteration ahead
  if (!layer) xn_reg = xptr[1];

  // One GRU step for this wave's role.  RB/WB = compile-time short offsets.
  // Prefetch index wraps at the tail: loads land in buffers never read again.
  #define STEP_BODY(RB, WB, F0, TT) do { \
    f16x8 H0 = *(const f16x8*)&Hown[(RB) + ra0], H1 = *(const f16x8*)&Hown[(RB) + ra1]; \
    f16x8 V0 = *(const f16x8*)&Vin[(RB) + ra0],  V1 = *(const f16x8*)&Vin[(RB) + ra1]; \
    if (!layer) { short h, l; split1(xn_reg, &h, &l); \
                  ((short*)xs)[(WB) + xwrH] = h; ((short*)xs)[(WB) + xwrL] = l; \
                  xn_reg = xptr[((TT) + 2) & (T_STEPS - 1)]; } \
    __builtin_amdgcn_s_setprio(1); \
    f32x4 sRh = MMC(H0, hrc0, bR4); MM(sRh, H1, hrc1); \
    f32x4 sRx = MMC(V0, irc0, z4);  MM(sRx, V1, irc1); \
    f32x4 sZh = MMC(H0, hzc0, bZ4); MM(sZh, H1, hzc1); \
    f32x4 sZx = MMC(V0, izc0, z4);  MM(sZx, V1, izc1); \
    f32x4 sHh = MMC(H0, hnc0, bH4); MM(sHh, H1, hnc1); \
    f32x4 sIx = MMC(V0, inc0, bI4); MM(sIx, V1, inc1); \
    __builtin_amdgcn_s_setprio(0); \
    float rr = sigm((sRh[0] + sRh[1]) + (sRx[0] + sRx[1])); \
    float zz = sigm((sZh[0] + sZh[1]) + (sZx[0] + sZx[1])); \
    float n = tanh_fast((sIx[0] + sIx[1]) + rr * (sHh[0] + sHh[1])); \
    float hnew = n + zz * (hp - n); \
    hp = ((F0) && layer && (TT) == 0) ? 0.f : hnew; \
    { short h, l; split1(hp, &h, &l); Hown[(WB) + hwrH] = h; Hown[(WB) + hwrL] = l; } \
    BARRIER(); \
  } while (0)

  #pragma unroll 1
  for (int t = 0; t < T_STEPS; t += 2) {
    STEP_BODY(1024, 0, 1, t);        // even t: read buf1, write buf0
    STEP_BODY(0, 1024, 0, t + 1);    // odd t:  read buf0, write buf1
  }
  #undef STEP_BODY

  // ---- epilogue: L1 waves compute layer1 step T-1 ----
  // after iter T-1 (WB=1024): hA[1] = hA(T-1), hB[1] = hB(T-2)
  if (layer) {
    const int rb = 1 << 10;
    f16x8 H0 = *(const f16x8*)&Hown[rb + ra0], H1 = *(const f16x8*)&Hown[rb + ra1];
    f16x8 V0 = *(const f16x8*)&Vin[rb + ra0],  V1 = *(const f16x8*)&Vin[rb + ra1];
    f32x4 sRh = MMC(H0, hrc0, bR4); MM(sRh, H1, hrc1);
    f32x4 sRx = MMC(V0, irc0, z4);  MM(sRx, V1, irc1);
    f32x4 sZh = MMC(H0, hzc0, bZ4); MM(sZh, H1, hzc1);
    f32x4 sZx = MMC(V0, izc0, z4);  MM(sZx, V1, izc1);
    f32x4 sHh = MMC(H0, hnc0, bH4); MM(sHh, H1, hnc1);
    f32x4 sIx = MMC(V0, inc0, bI4); MM(sIx, V1, inc1);
    float rr = sigm((sRh[0] + sRh[1]) + (sRx[0] + sRx[1]));
    float zz = sigm((sZh[0] + sZh[1]) + (sZx[0] + sZx[1]));
    float n = tanh_fast((sIx[0] + sIx[1]) + rr * (sHh[0] + sHh[1]));
    hp = n + zz * (hp - n);
    hfin[quad * 64 + jg] = hp;
  }
  __syncthreads();

  // ---- classifier on hfin = hB(T-1), fp32 ----
  if (tid < 128) {
    const int bb = tid >> 5, u = tid & 31;
    float acc = b1[u];
    const float* w1r = W1 + u * HID;
    #pragma unroll
    for (int k = 0; k < 64; ++k)
      acc = fmaf(w1r[k], hfin[bb * 64 + k], acc);
    msf[(bb << 5) + u] = fmaxf(acc, 0.f);
  }
  __syncthreads();
  if (tid < 16) {
    const int bb = tid >> 2, c = tid & 3;
    float acc = b2[c];
    const float* w2r = W2 + (c << 5);
    #pragma unroll
    for (int u = 0; u < 32; ++u)
      acc = fmaf(w2r[u], msf[(bb << 5) + u], acc);
    out[(size_t)(b0 + bb) * 4 + c] = acc;
  }
}

extern "C" void kernel_launch(void* const* d_in, const int* in_sizes, int n_in,
                              void* d_out, int out_size, void* d_ws, size_t ws_size,
                              hipStream_t stream) {
  const float* x    = (const float*)d_in[0];
  const float* Wih0 = (const float*)d_in[1];
  const float* Whh0 = (const float*)d_in[2];
  const float* bih0 = (const float*)d_in[3];
  const float* bhh0 = (const float*)d_in[4];
  const float* Wih1 = (const float*)d_in[5];
  const float* Whh1 = (const float*)d_in[6];
  const float* bih1 = (const float*)d_in[7];
  const float* bhh1 = (const float*)d_in[8];
  const float* W1   = (const float*)d_in[9];
  const float* b1   = (const float*)d_in[10];
  const float* W2   = (const float*)d_in[11];
  const float* b2   = (const float*)d_in[12];
  float* out = (float*)d_out;

  hipLaunchKernelGGL(gru_mfma, dim3(256), dim3(512), 0, stream,
                     x, Wih0, Whh0, bih0, bhh0, Wih1, Whh1, bih1, bhh1,
                     W1, b1, W2, b2, out);
}

// Round 14
// 367.722 us; speedup vs baseline: 1.0285x; 1.0285x over previous
//
#include <hip/hip_runtime.h>

#define T_STEPS 512
#define HID 64

typedef _Float16 f16x8 __attribute__((ext_vector_type(8)));
typedef float f32x4 __attribute__((ext_vector_type(4)));

__device__ __forceinline__ float sigm(float x) {
  return __builtin_amdgcn_rcpf(1.f + __expf(-x));
}
__device__ __forceinline__ float tanh_fast(float x) {
  return 1.f - 2.f * __builtin_amdgcn_rcpf(__expf(2.f * x) + 1.f);
}

// split fp32 -> fp16 hi (round-nearest) + fp16 lo (residual). hi+lo ~ v to 2^-22.
__device__ __forceinline__ void split1(float v, short* hi, short* lo) {
  _Float16 h = (_Float16)v;
  float r = v - (float)h;            // exact in fp32 (h within half-ulp of v)
  _Float16 l = (_Float16)r;
  union { _Float16 f; short s; } uh, ul;
  uh.f = h; ul.f = l;
  *hi = uh.s; *lo = ul.s;
}

__device__ __forceinline__ void cvt8(const float* __restrict__ p, f16x8& w) {
  float v[8];
  *(float4*)&v[0] = *(const float4*)p;
  *(float4*)&v[4] = *(const float4*)(p + 4);
  #pragma unroll
  for (int i = 0; i < 8; ++i) w[i] = (_Float16)v[i];
}

#define MM(acc, A, B) acc = __builtin_amdgcn_mfma_f32_16x16x32_f16((A), (B), (acc), 0, 0, 0)

// fp16 scheme (R12, best measured: 236.1 us rocprof): weights single fp16
// (2^-11 rel; replaces the bf16 hi+lo pair); values keep hi/lo M-rows
// (4b: v_hi, 4b+1: v_lo -> exact to ~2^-22). One depth-2 chain per
// gate-side: acc[0]+acc[1] = (vh+vl)·W16. 12 MFMA/wave = structural minimum.
#define GP2(acc, V0, V1, NM) do { MM(acc, V0, NM##c0); MM(acc, V1, NM##c1); } while (0)

#define WFRAG(NM, Wp, goff) \
  f16x8 NM##c0, NM##c1; \
  cvt8((Wp) + (goff) * (64 * HID) + wrowoff, NM##c0); \
  cvt8((Wp) + (goff) * (64 * HID) + wrowoff + 32, NM##c1)

// LDS A-matrices: logical [m(16)][k(64)] fp16 (bits in shorts), XOR-swizzled in
// 16B units: element idx = m*64 + (((k>>3) ^ (m&7))<<3) + (k&7). Conflict-free
// b128 reads. Batch b: v_hi at row 4b, v_lo at row 4b+1; rows 4b+2,3 stay zero.
//
// Structure (R12, restored verbatim after R13-R16 all measured flat-to-worse):
// wave specialization by layer (waves 0-3 = L0, 4-7 = L1; 2 waves/SIMD),
// single barrier/step, symmetric setprio around the MFMA cluster with the
// sigmoids between R/Z and N-side chains, biases in acc-init, 2x unrolled
// ping-pong with compile-time offsets.
__global__ __launch_bounds__(512, 2) void gru_mfma(
    const float* __restrict__ x,
    const float* __restrict__ Wih0, const float* __restrict__ Whh0,
    const float* __restrict__ bih0, const float* __restrict__ bhh0,
    const float* __restrict__ Wih1, const float* __restrict__ Whh1,
    const float* __restrict__ bih1, const float* __restrict__ bhh1,
    const float* __restrict__ W1, const float* __restrict__ b1,
    const float* __restrict__ W2, const float* __restrict__ b2,
    float* __restrict__ out)
{
  const int tid   = threadIdx.x;
  const int lane  = tid & 63;
  const int wv    = tid >> 6;      // 0..7
  const int wq    = wv & 3;        // j-chunk
  const int layer = wv >> 2;       // 0: GRU layer 0, 1: GRU layer 1
  const int nloc  = lane & 15;
  const int quad  = lane >> 4;
  const int b0    = blockIdx.x << 2;

  __shared__ __align__(16) short xs[2][1024];
  __shared__ __align__(16) short hA[2][1024];
  __shared__ __align__(16) short hB[2][1024];
  __shared__ float hfin[256];
  __shared__ float msf[128];

  // ---- per-layer weight/bias selection (wave-uniform) ----
  const float* Wih  = layer ? Wih1 : Wih0;
  const float* Whh  = layer ? Whh1 : Whh0;
  const float* bihp = layer ? bih1 : bih0;
  const float* bhhp = layer ? bhh1 : bhh0;

  const int wrowoff = (16 * wq + nloc) * HID + 8 * quad;
  WFRAG(ir, Wih, 0); WFRAG(iz, Wih, 1); WFRAG(in, Wih, 2);
  WFRAG(hr, Whh, 0); WFRAG(hz, Whh, 1); WFRAG(hn, Whh, 2);

  const int jg = 16 * wq + nloc;
  const float b_r = bihp[jg] + bhhp[jg];
  const float b_z = bihp[jg + 64] + bhhp[jg + 64];
  const float b_i = bihp[jg + 128], b_h = bhhp[jg + 128];

  // loop-invariant LDS indices (shorts)
  const int ra0 = nloc * 64 + (((quad    ) ^ (nloc & 7)) << 3);
  const int ra1 = nloc * 64 + (((quad + 4) ^ (nloc & 7)) << 3);
  const int hwrH = quad * 256 +      (((jg >> 3) ^ ( (quad & 1) << 2)     ) << 3) + (jg & 7);
  const int hwrL = quad * 256 + 64 + (((jg >> 3) ^ (((quad & 1) << 2) | 1)) << 3) + (jg & 7);
  const int xwrH = wq * 256 +      (((lane >> 3) ^ ( (wq & 1) << 2)     ) << 3) + (lane & 7);
  const int xwrL = wq * 256 + 64 + (((lane >> 3) ^ (((wq & 1) << 2) | 1)) << 3) + (lane & 7);

  // own-h array (written by this wave's role) and input array (read-only here):
  // L0: own = hA, in = xs;   L1: own = hB, in = hA.
  short* Hown = layer ? &hB[0][0] : &hA[0][0];
  short* Vin  = layer ? &hA[0][0] : &xs[0][0];

  const float* xptr = x + ((size_t)(b0 + wq) * HID + lane) * T_STEPS;

  for (int i = tid; i < 2048; i += 512) {
    ((short*)xs)[i] = 0; ((short*)hA)[i] = 0; ((short*)hB)[i] = 0;
  }
  __syncthreads();
  // iter 0 reads buffer 1: L0 seeds x(0) there (hA, hB stay zero = h(-1))
  if (!layer) { short h, l; split1(xptr[0], &h, &l); xs[1][xwrH] = h; xs[1][xwrL] = l; }
  __syncthreads();

  float hp = 0.f;   // L0: hA[quad][jg]; L1: hB[quad][jg], lagging one step

  // One GRU step for this wave's role.  RB/WB = compile-time short offsets.
  // x(TT+1) read wraps at TT=511: lands in a buffer never read again.
  #define STEP_BODY(RB, WB, F0, TT) do { \
    f16x8 H0 = *(const f16x8*)&Hown[(RB) + ra0], H1 = *(const f16x8*)&Hown[(RB) + ra1]; \
    f16x8 V0 = *(const f16x8*)&Vin[(RB) + ra0],  V1 = *(const f16x8*)&Vin[(RB) + ra1]; \
    float xn = 0.f; \
    if (!layer) xn = xptr[((TT) + 1) & (T_STEPS - 1)]; \
    f32x4 sRh = {b_r, 0.f, 0.f, 0.f}, sRx = {0.f, 0.f, 0.f, 0.f}; \
    f32x4 sZh = {b_z, 0.f, 0.f, 0.f}, sZx = {0.f, 0.f, 0.f, 0.f}; \
    f32x4 sHh = {b_h, 0.f, 0.f, 0.f}, sIx = {b_i, 0.f, 0.f, 0.f}; \
    __builtin_amdgcn_s_setprio(1); \
    GP2(sRh, H0, H1, hr); GP2(sRx, V0, V1, ir); \
    GP2(sZh, H0, H1, hz); GP2(sZx, V0, V1, iz); \
    float rr = sigm((sRx[0] + sRx[1]) + (sRh[0] + sRh[1])); \
    float zz = sigm((sZx[0] + sZx[1]) + (sZh[0] + sZh[1])); \
    GP2(sHh, H0, H1, hn); GP2(sIx, V0, V1, in); \
    __builtin_amdgcn_s_setprio(0); \
    float n = tanh_fast((sIx[0] + sIx[1]) + rr * (sHh[0] + sHh[1])); \
    float hnew = n + zz * (hp - n); \
    hp = ((F0) && layer && (TT) == 0) ? 0.f : hnew; \
    { short h, l; split1(hp, &h, &l); Hown[(WB) + hwrH] = h; Hown[(WB) + hwrL] = l; } \
    if (!layer) { short h, l; split1(xn, &h, &l); \
                  ((short*)xs)[(WB) + xwrH] = h; ((short*)xs)[(WB) + xwrL] = l; } \
    __syncthreads(); \
  } while (0)

  #pragma unroll 1
  for (int t = 0; t < T_STEPS; t += 2) {
    STEP_BODY(1024, 0, 1, t);        // even t: read buf1, write buf0
    STEP_BODY(0, 1024, 0, t + 1);    // odd t:  read buf0, write buf1
  }
  #undef STEP_BODY

  // ---- epilogue: L1 waves compute layer1 step T-1 ----
  // after iter T-1 (WB=1024): hA[1] = hA(T-1), hB[1] = hB(T-2)
  if (layer) {
    const int rb = 1 << 10;
    f16x8 H0 = *(const f16x8*)&Hown[rb + ra0], H1 = *(const f16x8*)&Hown[rb + ra1];
    f16x8 V0 = *(const f16x8*)&Vin[rb + ra0],  V1 = *(const f16x8*)&Vin[rb + ra1];
    f32x4 sRh = {b_r, 0.f, 0.f, 0.f}, sRx = {0.f, 0.f, 0.f, 0.f};
    f32x4 sZh = {b_z, 0.f, 0.f, 0.f}, sZx = {0.f, 0.f, 0.f, 0.f};
    f32x4 sHh = {b_h, 0.f, 0.f, 0.f}, sIx = {b_i, 0.f, 0.f, 0.f};
    GP2(sRh, H0, H1, hr); GP2(sRx, V0, V1, ir);
    GP2(sZh, H0, H1, hz); GP2(sZx, V0, V1, iz);
    float rr = sigm((sRx[0] + sRx[1]) + (sRh[0] + sRh[1]));
    float zz = sigm((sZx[0] + sZx[1]) + (sZh[0] + sZh[1]));
    GP2(sHh, H0, H1, hn); GP2(sIx, V0, V1, in);
    float n = tanh_fast((sIx[0] + sIx[1]) + rr * (sHh[0] + sHh[1]));
    hp = n + zz * (hp - n);
    hfin[quad * 64 + jg] = hp;
  }
  __syncthreads();

  // ---- classifier on hfin = hB(T-1), fp32 ----
  if (tid < 128) {
    const int bb = tid >> 5, u = tid & 31;
    float acc = b1[u];
    const float* w1r = W1 + u * HID;
    #pragma unroll
    for (int k = 0; k < 64; ++k)
      acc = fmaf(w1r[k], hfin[bb * 64 + k], acc);
    msf[(bb << 5) + u] = fmaxf(acc, 0.f);
  }
  __syncthreads();
  if (tid < 16) {
    const int bb = tid >> 2, c = tid & 3;
    float acc = b2[c];
    const float* w2r = W2 + (c << 5);
    #pragma unroll
    for (int u = 0; u < 32; ++u)
      acc = fmaf(w2r[u], msf[(bb << 5) + u], acc);
    out[(size_t)(b0 + bb) * 4 + c] = acc;
  }
}

extern "C" void kernel_launch(void* const* d_in, const int* in_sizes, int n_in,
                              void* d_out, int out_size, void* d_ws, size_t ws_size,
                              hipStream_t stream) {
  const float* x    = (const float*)d_in[0];
  const float* Wih0 = (const float*)d_in[1];
  const float* Whh0 = (const float*)d_in[2];
  const float* bih0 = (const float*)d_in[3];
  const float* bhh0 = (const float*)d_in[4];
  const float* Wih1 = (const float*)d_in[5];
  const float* Whh1 = (const float*)d_in[6];
  const float* bih1 = (const float*)d_in[7];
  const float* bhh1 = (const float*)d_in[8];
  const float* W1   = (const float*)d_in[9];
  const float* b1   = (const float*)d_in[10];
  const float* W2   = (const float*)d_in[11];
  const float* b2   = (const float*)d_in[12];
  float* out = (float*)d_out;

  hipLaunchKernelGGL(gru_mfma, dim3(256), dim3(512), 0, stream,
                     x, Wih0, Whh0, bih0, bhh0, Wih1, Whh1, bih1, bhh1,
                     W1, b1, W2, b2, out);
}